// Round 3
// baseline (529.393 us; speedup 1.0000x reference)
//
#include <hip/hip_runtime.h>
#include <hip/hip_bf16.h>

typedef __bf16 bf16;
typedef __bf16 bf16x4 __attribute__((ext_vector_type(4)));
typedef __bf16 bf16x8 __attribute__((ext_vector_type(8)));
typedef float  f32x4  __attribute__((ext_vector_type(4)));

#define DEV static __device__ __forceinline__

static constexpr int Bsz = 4, T = 2048, C = 1024, H = 16;
static constexpr int M  = Bsz * T;   // 8192
static constexpr int N1 = 3 * C;     // 3072
static constexpr float SM_SCALE = 0.125f;  // D^-0.5 = 2^-3, exact in bf16

// async global->LDS, 16B per lane. LDS dest is wave-uniform base + lane*16.
DEV void gload16(const bf16* g, bf16* l) {
  __builtin_amdgcn_global_load_lds(
      (const __attribute__((address_space(1))) void*)g,
      (__attribute__((address_space(3))) void*)l, 16, 0, 0);
}

// ---------------------------------------------------------------------------
// fp32 -> bf16 convert (vectorized, memory-bound)
// ---------------------------------------------------------------------------
__launch_bounds__(256)
__global__ void convert_kernel(const float* __restrict__ in, bf16* __restrict__ out) {
  const size_t i = ((size_t)blockIdx.x * 256 + threadIdx.x) * 8;
  f32x4 a = *(const f32x4*)(in + i);
  f32x4 b = *(const f32x4*)(in + i + 4);
  *(bf16x4*)(out + i)     = __builtin_convertvector(a, bf16x4);
  *(bf16x4*)(out + i + 4) = __builtin_convertvector(b, bf16x4);
}

// ---------------------------------------------------------------------------
// Transpose + fp32->bf16 convert:  in[K][N] (fp32) -> out[N][K] (bf16)
// ---------------------------------------------------------------------------
__launch_bounds__(256)
__global__ void transpose_conv_kernel(const float* __restrict__ in,
                                      bf16* __restrict__ out, int K, int N) {
  __shared__ float t[32][33];
  const int n0 = blockIdx.x * 32, k0 = blockIdx.y * 32;
  const int tx = threadIdx.x & 31, ty = threadIdx.x >> 5;  // ty in 0..7
#pragma unroll
  for (int j = 0; j < 4; ++j)
    t[ty + j * 8][tx] = in[(size_t)(k0 + ty + j * 8) * N + n0 + tx];
  __syncthreads();
#pragma unroll
  for (int j = 0; j < 4; ++j)
    out[(size_t)(n0 + ty + j * 8) * K + k0 + tx] = (bf16)t[tx][ty + j * 8];
}

// ---------------------------------------------------------------------------
// GEMM (m97 structure): Out[M][N] = A[M][K] @ Bt[N][K]^T + bias[N]
// A, Bt bf16. 128x128 tile, BK=64, 256 thr = 4 waves (2x2), wave does 64x64.
// Staging via global_load_lds width=16, LINEAR LDS (T2 swizzle is null at
// 128^2 + 2-phase per regime gate). 2 barriers per K-step.
// MFMA 16x16x32 bf16. A/B frag: row=l&15, k=(l>>4)*8+j.
// C/D: col=l&15, row=(l>>4)*4+r  [m89-verified].
// ---------------------------------------------------------------------------
template <bool OUT_BF16>
__launch_bounds__(256)
__global__ void gemm_kernel(const bf16* __restrict__ A,
                            const bf16* __restrict__ Bt,
                            const float* __restrict__ bias,
                            void* __restrict__ Out, int Ndim, int Kdim) {
  __shared__ bf16 lds_a[128 * 64];
  __shared__ bf16 lds_b[128 * 64];
  const int tid = threadIdx.x;
  const int l = tid & 63, wid = tid >> 6;
  const int wm = wid >> 1, wn = wid & 1;
  const int lr = l & 15, lh = l >> 4;
  const int m0 = blockIdx.x * 128, n0 = blockIdx.y * 128;
  // staging decomposition: chunk c covers LDS rows c*8..c*8+7 (1 KiB);
  // lane i supplies 16B at row c*8+(i>>3), elems (i&7)*8.
  const int r8 = l >> 3, g8 = (l & 7) * 8;

  f32x4 acc[4][4] = {};

  for (int k0 = 0; k0 < Kdim; k0 += 64) {
    __syncthreads();  // protect LDS from previous iteration's readers
#pragma unroll
    for (int i = 0; i < 4; ++i) {
      const int c = wid * 4 + i;
      const int row = c * 8 + r8;
      gload16(A  + (size_t)(m0 + row) * Kdim + k0 + g8, &lds_a[c * 512]);
      gload16(Bt + (size_t)(n0 + row) * Kdim + k0 + g8, &lds_b[c * 512]);
    }
    __syncthreads();  // compiler emits s_waitcnt vmcnt(0) before s_barrier
#pragma unroll
    for (int kk = 0; kk < 2; ++kk) {
      bf16x8 af[4], bfr[4];
#pragma unroll
      for (int mi = 0; mi < 4; ++mi)
        af[mi] = *(const bf16x8*)&lds_a[(wm * 64 + mi * 16 + lr) * 64 + kk * 32 + lh * 8];
#pragma unroll
      for (int ni = 0; ni < 4; ++ni)
        bfr[ni] = *(const bf16x8*)&lds_b[(wn * 64 + ni * 16 + lr) * 64 + kk * 32 + lh * 8];
#pragma unroll
      for (int mi = 0; mi < 4; ++mi)
#pragma unroll
        for (int ni = 0; ni < 4; ++ni)
          acc[mi][ni] = __builtin_amdgcn_mfma_f32_16x16x32_bf16(
              af[mi], bfr[ni], acc[mi][ni], 0, 0, 0);
    }
  }
  // ---- epilogue: bias + store
#pragma unroll
  for (int ni = 0; ni < 4; ++ni) {
    int col = n0 + wn * 64 + ni * 16 + lr;
    float bv = bias[col];
#pragma unroll
    for (int mi = 0; mi < 4; ++mi) {
#pragma unroll
      for (int r = 0; r < 4; ++r) {
        int row = m0 + wm * 64 + mi * 16 + lh * 4 + r;
        float v = acc[mi][ni][r] + bv;
        if (OUT_BF16)
          ((bf16*)Out)[(size_t)row * Ndim + col] = (bf16)v;
        else
          ((float*)Out)[(size_t)row * Ndim + col] = v;
      }
    }
  }
}

// ---------------------------------------------------------------------------
// Flash attention (causal). qkv bf16 [B*T][3*C] rows; out bf16 [B*T][C].
// Block: 4 waves x 16 q-rows = 64 q-rows of one (b,h). K/V tiles of 64 keys.
// LDS tiles XOR-swizzled (G4: row-major D=64 frag reads are bank-conflicted).
// Grid (qt, bh): consecutive blocks share one head's K/V stream (L2 locality).
// ---------------------------------------------------------------------------
DEV float rmax16(float v) {
  v = fmaxf(v, __shfl_xor(v, 1));
  v = fmaxf(v, __shfl_xor(v, 2));
  v = fmaxf(v, __shfl_xor(v, 4));
  v = fmaxf(v, __shfl_xor(v, 8));
  return v;
}
DEV float rsum16(float v) {
  v += __shfl_xor(v, 1);
  v += __shfl_xor(v, 2);
  v += __shfl_xor(v, 4);
  v += __shfl_xor(v, 8);
  return v;
}

__launch_bounds__(256)
__global__ void attn_kernel(const bf16* __restrict__ qkv, bf16* __restrict__ out) {
  __shared__ bf16 lds_k[64 * 64];
  __shared__ bf16 lds_vt[64 * 64];
  __shared__ bf16 lds_p[4][16 * 64];
  const int tid = threadIdx.x, l = tid & 63, w = tid >> 6;
  const int lr = l & 15, lh = l >> 4;
  const int qt = blockIdx.x;                       // q-tile (fast dim)
  const int bh = blockIdx.y, b = bh >> 4, h = bh & 15;
  const size_t RS = 3 * C;  // qkv row stride (elems)
  const bf16* base  = qkv + (size_t)b * T * RS;
  const bf16* kbase = base + C + h * 64;
  const bf16* vbase = base + 2 * C + h * 64;

  // Q fragments (held in regs for whole kernel), pre-scaled by 2^-3 (exact)
  const int q16 = qt * 64 + w * 16;
  bf16x8 qf[2];
#pragma unroll
  for (int kk = 0; kk < 2; ++kk) {
    bf16x8 qv = *(const bf16x8*)(base + (size_t)(q16 + lr) * RS + h * 64 + kk * 32 + lh * 8);
#pragma unroll
    for (int j = 0; j < 8; ++j) qf[kk][j] = (bf16)((float)qv[j] * SM_SCALE);
  }

  float mrow[4], lrow[4];
  f32x4 o[4] = {};
#pragma unroll
  for (int r = 0; r < 4; ++r) { mrow[r] = -__builtin_inff(); lrow[r] = 0.f; }

  for (int kt = 0; kt <= qt; ++kt) {
    __syncthreads();
    // ---- stage K tile [64 keys][64 d]
#pragma unroll
    for (int i = 0; i < 2; ++i) {
      int slot = i * 256 + tid;
      int row = slot >> 3, s = slot & 7;
      bf16x8 v = *(const bf16x8*)(kbase + (size_t)(kt * 64 + row) * RS + s * 8);
      *(bf16x8*)&lds_k[(row * 64 + s * 8) ^ ((row & 7) << 3)] = v;
    }
    // ---- stage V^T tile [64 d][64 keys] (scatter transpose)
#pragma unroll
    for (int i = 0; i < 2; ++i) {
      int slot = i * 256 + tid;
      int key = slot >> 3, s = slot & 7;
      bf16x8 v = *(const bf16x8*)(vbase + (size_t)(kt * 64 + key) * RS + s * 8);
#pragma unroll
      for (int j = 0; j < 8; ++j) {
        int d = s * 8 + j;
        lds_vt[(d * 64 + key) ^ ((d & 7) << 3)] = v[j];
      }
    }
    __syncthreads();

    // ---- S = (Q*scale) K^T  (4 key-frags x 2 k-steps)
    f32x4 s4[4] = {};
#pragma unroll
    for (int kk = 0; kk < 2; ++kk) {
#pragma unroll
      for (int kn = 0; kn < 4; ++kn) {
        int key = kn * 16 + lr;
        bf16x8 kf = *(const bf16x8*)&lds_k[(key * 64 + kk * 32 + lh * 8) ^ ((key & 7) << 3)];
        s4[kn] = __builtin_amdgcn_mfma_f32_16x16x32_bf16(qf[kk], kf, s4[kn], 0, 0, 0);
      }
    }
    // ---- causal mask (only diagonal tile needs masking)
    if (kt == qt) {
#pragma unroll
      for (int kn = 0; kn < 4; ++kn)
#pragma unroll
        for (int r = 0; r < 4; ++r)
          if ((kn * 16 + lr) > (w * 16 + lh * 4 + r)) s4[kn][r] = -__builtin_inff();
    }
    // ---- online softmax (all 64 lanes active; 16-lane-group reductions)
    float alpha[4];
#pragma unroll
    for (int r = 0; r < 4; ++r) {
      float pm = fmaxf(fmaxf(s4[0][r], s4[1][r]), fmaxf(s4[2][r], s4[3][r]));
      pm = rmax16(pm);
      float mnew = fmaxf(mrow[r], pm);
      alpha[r] = __expf(mrow[r] - mnew);
      mrow[r] = mnew;
      float acc = 0.f;
#pragma unroll
      for (int kn = 0; kn < 4; ++kn) {
        float p = __expf(s4[kn][r] - mnew);
        s4[kn][r] = p;
        acc += p;
      }
      lrow[r] = lrow[r] * alpha[r] + rsum16(acc);
    }
#pragma unroll
    for (int ni = 0; ni < 4; ++ni)
#pragma unroll
      for (int r = 0; r < 4; ++r) o[ni][r] *= alpha[r];
    // ---- P -> LDS (per-wave buffer), bf16
#pragma unroll
    for (int kn = 0; kn < 4; ++kn)
#pragma unroll
      for (int r = 0; r < 4; ++r) {
        int q = lh * 4 + r, key = kn * 16 + lr;
        lds_p[w][(q * 64 + key) ^ ((q & 7) << 3)] = (bf16)s4[kn][r];
      }
    // ---- O += P V  (same-wave LDS write->read ordered via lgkmcnt)
#pragma unroll
    for (int kk = 0; kk < 2; ++kk) {
      bf16x8 pf = *(const bf16x8*)&lds_p[w][(lr * 64 + kk * 32 + lh * 8) ^ ((lr & 7) << 3)];
#pragma unroll
      for (int ni = 0; ni < 4; ++ni) {
        int d = ni * 16 + lr;
        bf16x8 vf = *(const bf16x8*)&lds_vt[(d * 64 + kk * 32 + lh * 8) ^ ((d & 7) << 3)];
        o[ni] = __builtin_amdgcn_mfma_f32_16x16x32_bf16(pf, vf, o[ni], 0, 0, 0);
      }
    }
  }
  // ---- epilogue: normalize, store merged-head layout [B*T][C]
  bf16* op = out + (size_t)b * T * C + h * 64;
#pragma unroll
  for (int ni = 0; ni < 4; ++ni)
#pragma unroll
    for (int r = 0; r < 4; ++r) {
      int q = q16 + lh * 4 + r;
      op[(size_t)q * C + ni * 16 + lr] = (bf16)(o[ni][r] / lrow[r]);
    }
}

// ---------------------------------------------------------------------------
extern "C" void kernel_launch(void* const* d_in, const int* in_sizes, int n_in,
                              void* d_out, int out_size, void* d_ws, size_t ws_size,
                              hipStream_t stream) {
  const float* x     = (const float*)d_in[0];
  const float* Wqkv  = (const float*)d_in[1];
  const float* bqkv  = (const float*)d_in[2];
  const float* Wproj = (const float*)d_in[3];
  const float* bproj = (const float*)d_in[4];
  float* out = (float*)d_out;

  char* ws = (char*)d_ws;
  bf16* qkv      = (bf16*)(ws);             // 8192*3072*2 = 50331648 B
  bf16* wqkvt    = (bf16*)(ws + 50331648);  // 3072*1024*2 =  6291456 B
  bf16* wprojt   = (bf16*)(ws + 56623104);  // 1024*1024*2 =  2097152 B
  bf16* attn_out = (bf16*)(ws + 58720256);  // 8192*1024*2 = 16777216 B (total 72 MiB)
  bf16* x_bf16   = attn_out;  // aliased: x_bf16 dead before attn writes attn_out

  // 1) x -> bf16 (one pass), weight transposes (fp32 -> bf16, [K][N] -> [N][K])
  convert_kernel<<<dim3(M * C / (256 * 8)), 256, 0, stream>>>(x, x_bf16);
  transpose_conv_kernel<<<dim3(N1 / 32, C / 32), 256, 0, stream>>>(Wqkv, wqkvt, C, N1);
  transpose_conv_kernel<<<dim3(C / 32, C / 32), 256, 0, stream>>>(Wproj, wprojt, C, C);
  // 2) QKV projection: qkv[B*T][3C] bf16
  gemm_kernel<true><<<dim3(M / 128, N1 / 128), 256, 0, stream>>>(
      x_bf16, wqkvt, bqkv, qkv, N1, C);
  // 3) causal flash attention
  attn_kernel<<<dim3(T / 64, Bsz * H), 256, 0, stream>>>(qkv, attn_out);
  // 4) output projection (fp32 out)
  gemm_kernel<false><<<dim3(M / 128, C / 128), 256, 0, stream>>>(
      attn_out, wprojt, bproj, out, C, C);
}

// Round 4
// 453.800 us; speedup vs baseline: 1.1666x; 1.1666x over previous
//
#include <hip/hip_runtime.h>
#include <hip/hip_bf16.h>

typedef __bf16 bf16;
typedef __bf16 bf16x4 __attribute__((ext_vector_type(4)));
typedef __bf16 bf16x8 __attribute__((ext_vector_type(8)));
typedef float  f32x4  __attribute__((ext_vector_type(4)));

#define DEV static __device__ __forceinline__

static constexpr int Bsz = 4, T = 2048, C = 1024, H = 16;
static constexpr int M  = Bsz * T;   // 8192
static constexpr int N1 = 3 * C;     // 3072
static constexpr float SM_SCALE = 0.125f;  // D^-0.5 = 2^-3, exact in bf16

// async global->LDS, 16B per lane. LDS dest is wave-uniform base + lane*16.
DEV void gload16(const bf16* g, bf16* l) {
  __builtin_amdgcn_global_load_lds(
      (const __attribute__((address_space(1))) void*)g,
      (__attribute__((address_space(3))) void*)l, 16, 0, 0);
}

// ---------------------------------------------------------------------------
// fp32 -> bf16 convert (vectorized, memory-bound)
// ---------------------------------------------------------------------------
__launch_bounds__(256)
__global__ void convert_kernel(const float* __restrict__ in, bf16* __restrict__ out) {
  const size_t i = ((size_t)blockIdx.x * 256 + threadIdx.x) * 8;
  f32x4 a = *(const f32x4*)(in + i);
  f32x4 b = *(const f32x4*)(in + i + 4);
  *(bf16x4*)(out + i)     = __builtin_convertvector(a, bf16x4);
  *(bf16x4*)(out + i + 4) = __builtin_convertvector(b, bf16x4);
}

// ---------------------------------------------------------------------------
// Transpose + fp32->bf16 convert:  in[K][N] (fp32) -> out[N][K] (bf16)
// ---------------------------------------------------------------------------
__launch_bounds__(256)
__global__ void transpose_conv_kernel(const float* __restrict__ in,
                                      bf16* __restrict__ out, int K, int N) {
  __shared__ float t[32][33];
  const int n0 = blockIdx.x * 32, k0 = blockIdx.y * 32;
  const int tx = threadIdx.x & 31, ty = threadIdx.x >> 5;  // ty in 0..7
#pragma unroll
  for (int j = 0; j < 4; ++j)
    t[ty + j * 8][tx] = in[(size_t)(k0 + ty + j * 8) * N + n0 + tx];
  __syncthreads();
#pragma unroll
  for (int j = 0; j < 4; ++j)
    out[(size_t)(n0 + ty + j * 8) * K + k0 + tx] = (bf16)t[tx][ty + j * 8];
}

// ---------------------------------------------------------------------------
// GEMM (m97 structure): Out[M][N] = A[M][K] @ Bt[N][K]^T + bias[N]
// (unchanged from round 3 — passed, ~180us combined; attn is the target)
// ---------------------------------------------------------------------------
template <bool OUT_BF16>
__launch_bounds__(256)
__global__ void gemm_kernel(const bf16* __restrict__ A,
                            const bf16* __restrict__ Bt,
                            const float* __restrict__ bias,
                            void* __restrict__ Out, int Ndim, int Kdim) {
  __shared__ bf16 lds_a[128 * 64];
  __shared__ bf16 lds_b[128 * 64];
  const int tid = threadIdx.x;
  const int l = tid & 63, wid = tid >> 6;
  const int wm = wid >> 1, wn = wid & 1;
  const int lr = l & 15, lh = l >> 4;
  const int m0 = blockIdx.x * 128, n0 = blockIdx.y * 128;
  const int r8 = l >> 3, g8 = (l & 7) * 8;

  f32x4 acc[4][4] = {};

  for (int k0 = 0; k0 < Kdim; k0 += 64) {
    __syncthreads();
#pragma unroll
    for (int i = 0; i < 4; ++i) {
      const int c = wid * 4 + i;
      const int row = c * 8 + r8;
      gload16(A  + (size_t)(m0 + row) * Kdim + k0 + g8, &lds_a[c * 512]);
      gload16(Bt + (size_t)(n0 + row) * Kdim + k0 + g8, &lds_b[c * 512]);
    }
    __syncthreads();
#pragma unroll
    for (int kk = 0; kk < 2; ++kk) {
      bf16x8 af[4], bfr[4];
#pragma unroll
      for (int mi = 0; mi < 4; ++mi)
        af[mi] = *(const bf16x8*)&lds_a[(wm * 64 + mi * 16 + lr) * 64 + kk * 32 + lh * 8];
#pragma unroll
      for (int ni = 0; ni < 4; ++ni)
        bfr[ni] = *(const bf16x8*)&lds_b[(wn * 64 + ni * 16 + lr) * 64 + kk * 32 + lh * 8];
#pragma unroll
      for (int mi = 0; mi < 4; ++mi)
#pragma unroll
        for (int ni = 0; ni < 4; ++ni)
          acc[mi][ni] = __builtin_amdgcn_mfma_f32_16x16x32_bf16(
              af[mi], bfr[ni], acc[mi][ni], 0, 0, 0);
    }
  }
#pragma unroll
  for (int ni = 0; ni < 4; ++ni) {
    int col = n0 + wn * 64 + ni * 16 + lr;
    float bv = bias[col];
#pragma unroll
    for (int mi = 0; mi < 4; ++mi) {
#pragma unroll
      for (int r = 0; r < 4; ++r) {
        int row = m0 + wm * 64 + mi * 16 + lh * 4 + r;
        float v = acc[mi][ni][r] + bv;
        if (OUT_BF16)
          ((bf16*)Out)[(size_t)row * Ndim + col] = (bf16)v;
        else
          ((float*)Out)[(size_t)row * Ndim + col] = v;
      }
    }
  }
}

// ---------------------------------------------------------------------------
// Flash attention (causal), double-buffered + async-stage split (T14).
// Per iter: issue global->reg prefetch of tile kt+1, compute tile kt from
// LDS[buf], then write regs->LDS[buf^1], one barrier, swap. Global-load
// latency hides under QK/softmax/PV compute.
// V^T write swizzle ((d&7)^(d>>3))<<3: conflict-free scatter (2-way) AND
// conflict-free 16B reads (old ((d&7)<<3) was 16-way on stores: d&7 const
// across lanes at fixed unroll step).
// qt reversed: longest blocks launch first (causal tail packing).
// ---------------------------------------------------------------------------
DEV float rmax16(float v) {
  v = fmaxf(v, __shfl_xor(v, 1));
  v = fmaxf(v, __shfl_xor(v, 2));
  v = fmaxf(v, __shfl_xor(v, 4));
  v = fmaxf(v, __shfl_xor(v, 8));
  return v;
}
DEV float rsum16(float v) {
  v += __shfl_xor(v, 1);
  v += __shfl_xor(v, 2);
  v += __shfl_xor(v, 4);
  v += __shfl_xor(v, 8);
  return v;
}

DEV int vswz(int d, int key) {  // elem index into V^T tile [64 d][64 key]
  return (d * 64 + key) ^ ((((d & 7) ^ (d >> 3)) & 7) << 3);
}

__launch_bounds__(256)
__global__ void attn_kernel(const bf16* __restrict__ qkv, bf16* __restrict__ out) {
  __shared__ bf16 lds_k[2][64 * 64];
  __shared__ bf16 lds_vt[2][64 * 64];
  __shared__ bf16 lds_p[4][16 * 64];
  const int tid = threadIdx.x, l = tid & 63, w = tid >> 6;
  const int lr = l & 15, lh = l >> 4;
  const int qt = gridDim.x - 1 - blockIdx.x;       // longest-first
  const int bh = blockIdx.y, b = bh >> 4, h = bh & 15;
  const size_t RS = 3 * C;  // qkv row stride (elems)
  const bf16* base  = qkv + (size_t)b * T * RS;
  const bf16* kbase = base + C + h * 64;
  const bf16* vbase = base + 2 * C + h * 64;
  const int srow = tid >> 3;   // staging: row 0..31 (+32 on second step)
  const int ss   = tid & 7;    // staging: 8-elem group within row

  // Q fragments (regs, whole kernel), pre-scaled by 2^-3 (exact in bf16)
  const int q16 = qt * 64 + w * 16;
  bf16x8 qf[2];
#pragma unroll
  for (int kk = 0; kk < 2; ++kk) {
    bf16x8 qv = *(const bf16x8*)(base + (size_t)(q16 + lr) * RS + h * 64 + kk * 32 + lh * 8);
#pragma unroll
    for (int j = 0; j < 8; ++j) qf[kk][j] = (bf16)((float)qv[j] * SM_SCALE);
  }

  float mrow[4], lrow[4];
  f32x4 o[4] = {};
#pragma unroll
  for (int r = 0; r < 4; ++r) { mrow[r] = -__builtin_inff(); lrow[r] = 0.f; }

  // ---- prologue: stage tile 0 into buf 0
  bf16x8 pk[2], pv[2];
#pragma unroll
  for (int i = 0; i < 2; ++i) {
    int row = i * 32 + srow;
    pk[i] = *(const bf16x8*)(kbase + (size_t)row * RS + ss * 8);
    pv[i] = *(const bf16x8*)(vbase + (size_t)row * RS + ss * 8);
  }
#pragma unroll
  for (int i = 0; i < 2; ++i) {
    int row = i * 32 + srow;
    *(bf16x8*)&lds_k[0][(row * 64 + ss * 8) ^ ((row & 7) << 3)] = pk[i];
#pragma unroll
    for (int j = 0; j < 8; ++j) lds_vt[0][vswz(ss * 8 + j, row)] = pv[i][j];
  }
  __syncthreads();

  int buf = 0;
  for (int kt = 0; kt <= qt; ++kt) {
    const bf16* kb = &lds_k[buf][0];
    const bf16* vb = &lds_vt[buf][0];
    // ---- issue prefetch of tile kt+1 (latency hides under compute below)
    if (kt < qt) {
#pragma unroll
      for (int i = 0; i < 2; ++i) {
        int row = i * 32 + srow;
        pk[i] = *(const bf16x8*)(kbase + (size_t)((kt + 1) * 64 + row) * RS + ss * 8);
        pv[i] = *(const bf16x8*)(vbase + (size_t)((kt + 1) * 64 + row) * RS + ss * 8);
      }
    }

    // ---- S = (Q*scale) K^T  (4 key-frags x 2 k-steps)
    f32x4 s4[4] = {};
#pragma unroll
    for (int kk = 0; kk < 2; ++kk) {
#pragma unroll
      for (int kn = 0; kn < 4; ++kn) {
        int key = kn * 16 + lr;
        bf16x8 kf = *(const bf16x8*)&kb[(key * 64 + kk * 32 + lh * 8) ^ ((key & 7) << 3)];
        s4[kn] = __builtin_amdgcn_mfma_f32_16x16x32_bf16(qf[kk], kf, s4[kn], 0, 0, 0);
      }
    }
    // ---- causal mask (diagonal tile only)
    if (kt == qt) {
#pragma unroll
      for (int kn = 0; kn < 4; ++kn)
#pragma unroll
        for (int r = 0; r < 4; ++r)
          if ((kn * 16 + lr) > (w * 16 + lh * 4 + r)) s4[kn][r] = -__builtin_inff();
    }
    // ---- online softmax (16-lane-group reductions)
    float alpha[4];
#pragma unroll
    for (int r = 0; r < 4; ++r) {
      float pm = fmaxf(fmaxf(s4[0][r], s4[1][r]), fmaxf(s4[2][r], s4[3][r]));
      pm = rmax16(pm);
      float mnew = fmaxf(mrow[r], pm);
      alpha[r] = __expf(mrow[r] - mnew);
      mrow[r] = mnew;
      float acc = 0.f;
#pragma unroll
      for (int kn = 0; kn < 4; ++kn) {
        float p = __expf(s4[kn][r] - mnew);
        s4[kn][r] = p;
        acc += p;
      }
      lrow[r] = lrow[r] * alpha[r] + rsum16(acc);
    }
#pragma unroll
    for (int ni = 0; ni < 4; ++ni)
#pragma unroll
      for (int r = 0; r < 4; ++r) o[ni][r] *= alpha[r];
    // ---- P -> LDS (per-wave buffer), bf16
#pragma unroll
    for (int kn = 0; kn < 4; ++kn)
#pragma unroll
      for (int r = 0; r < 4; ++r) {
        int q = lh * 4 + r, key = kn * 16 + lr;
        lds_p[w][(q * 64 + key) ^ ((q & 7) << 3)] = (bf16)s4[kn][r];
      }
    // ---- O += P V
#pragma unroll
    for (int kk = 0; kk < 2; ++kk) {
      bf16x8 pf = *(const bf16x8*)&lds_p[w][(lr * 64 + kk * 32 + lh * 8) ^ ((lr & 7) << 3)];
#pragma unroll
      for (int ni = 0; ni < 4; ++ni) {
        int d = ni * 16 + lr;
        bf16x8 vf = *(const bf16x8*)&vb[vswz(d, 0) + kk * 32 + lh * 8 - 0];
        // NOTE: vswz applies XOR only to bits 0..5 (key part); recompute fully:
        vf = *(const bf16x8*)&vb[vswz(d, kk * 32 + lh * 8)];
        o[ni] = __builtin_amdgcn_mfma_f32_16x16x32_bf16(pf, vf, o[ni], 0, 0, 0);
      }
    }

    // ---- write prefetched tile into buf^1, single barrier, swap
    if (kt < qt) {
#pragma unroll
      for (int i = 0; i < 2; ++i) {
        int row = i * 32 + srow;
        *(bf16x8*)&lds_k[buf ^ 1][(row * 64 + ss * 8) ^ ((row & 7) << 3)] = pk[i];
#pragma unroll
        for (int j = 0; j < 8; ++j) lds_vt[buf ^ 1][vswz(ss * 8 + j, row)] = pv[i][j];
      }
      __syncthreads();
      buf ^= 1;
    }
  }
  // ---- epilogue: normalize, store merged-head layout [B*T][C]
  bf16* op = out + (size_t)b * T * C + h * 64;
#pragma unroll
  for (int ni = 0; ni < 4; ++ni)
#pragma unroll
    for (int r = 0; r < 4; ++r) {
      int q = q16 + lh * 4 + r;
      op[(size_t)q * C + ni * 16 + lr] = (bf16)(o[ni][r] / lrow[r]);
    }
}

// ---------------------------------------------------------------------------
extern "C" void kernel_launch(void* const* d_in, const int* in_sizes, int n_in,
                              void* d_out, int out_size, void* d_ws, size_t ws_size,
                              hipStream_t stream) {
  const float* x     = (const float*)d_in[0];
  const float* Wqkv  = (const float*)d_in[1];
  const float* bqkv  = (const float*)d_in[2];
  const float* Wproj = (const float*)d_in[3];
  const float* bproj = (const float*)d_in[4];
  float* out = (float*)d_out;

  char* ws = (char*)d_ws;
  bf16* qkv      = (bf16*)(ws);             // 8192*3072*2 = 50331648 B
  bf16* wqkvt    = (bf16*)(ws + 50331648);  // 3072*1024*2 =  6291456 B
  bf16* wprojt   = (bf16*)(ws + 56623104);  // 1024*1024*2 =  2097152 B
  bf16* attn_out = (bf16*)(ws + 58720256);  // 8192*1024*2 = 16777216 B (total 72 MiB)
  bf16* x_bf16   = attn_out;  // aliased: x_bf16 dead before attn writes attn_out

  convert_kernel<<<dim3(M * C / (256 * 8)), 256, 0, stream>>>(x, x_bf16);
  transpose_conv_kernel<<<dim3(N1 / 32, C / 32), 256, 0, stream>>>(Wqkv, wqkvt, C, N1);
  transpose_conv_kernel<<<dim3(C / 32, C / 32), 256, 0, stream>>>(Wproj, wprojt, C, C);
  gemm_kernel<true><<<dim3(M / 128, N1 / 128), 256, 0, stream>>>(
      x_bf16, wqkvt, bqkv, qkv, N1, C);
  attn_kernel<<<dim3(T / 64, Bsz * H), 256, 0, stream>>>(qkv, attn_out);
  gemm_kernel<false><<<dim3(M / 128, C / 128), 256, 0, stream>>>(
      attn_out, wprojt, bproj, out, C, C);
}

// Round 5
// 354.721 us; speedup vs baseline: 1.4924x; 1.2793x over previous
//
#include <hip/hip_runtime.h>
#include <hip/hip_bf16.h>

typedef __bf16 bf16;
typedef __bf16 bf16x4 __attribute__((ext_vector_type(4)));
typedef __bf16 bf16x8 __attribute__((ext_vector_type(8)));
typedef float  f32x4  __attribute__((ext_vector_type(4)));

#define DEV static __device__ __forceinline__

static constexpr int Bsz = 4, T = 2048, C = 1024, H = 16;
static constexpr int M  = Bsz * T;   // 8192
static constexpr int N1 = 3 * C;     // 3072
static constexpr float SM_SCALE = 0.125f;  // D^-0.5 = 2^-3, exact in bf16

// async global->LDS, 16B per lane. LDS dest is wave-uniform base + lane*16.
DEV void gload16(const bf16* g, bf16* l) {
  __builtin_amdgcn_global_load_lds(
      (const __attribute__((address_space(1))) void*)g,
      (__attribute__((address_space(3))) void*)l, 16, 0, 0);
}

// ---------------------------------------------------------------------------
// fp32 -> bf16 convert (vectorized, memory-bound)
// ---------------------------------------------------------------------------
__launch_bounds__(256)
__global__ void convert_kernel(const float* __restrict__ in, bf16* __restrict__ out) {
  const size_t i = ((size_t)blockIdx.x * 256 + threadIdx.x) * 8;
  f32x4 a = *(const f32x4*)(in + i);
  f32x4 b = *(const f32x4*)(in + i + 4);
  *(bf16x4*)(out + i)     = __builtin_convertvector(a, bf16x4);
  *(bf16x4*)(out + i + 4) = __builtin_convertvector(b, bf16x4);
}

// ---------------------------------------------------------------------------
// Transpose + fp32->bf16 convert:  in[K][N] (fp32) -> out[N][K] (bf16)
// ---------------------------------------------------------------------------
__launch_bounds__(256)
__global__ void transpose_conv_kernel(const float* __restrict__ in,
                                      bf16* __restrict__ out, int K, int N) {
  __shared__ float t[32][33];
  const int n0 = blockIdx.x * 32, k0 = blockIdx.y * 32;
  const int tx = threadIdx.x & 31, ty = threadIdx.x >> 5;  // ty in 0..7
#pragma unroll
  for (int j = 0; j < 4; ++j)
    t[ty + j * 8][tx] = in[(size_t)(k0 + ty + j * 8) * N + n0 + tx];
  __syncthreads();
#pragma unroll
  for (int j = 0; j < 4; ++j)
    out[(size_t)(n0 + ty + j * 8) * K + k0 + tx] = (bf16)t[tx][ty + j * 8];
}

// ---------------------------------------------------------------------------
// GEMM (m97 structure): Out[M][N] = A[M][K] @ Bt[N][K]^T + bias[N]
// (unchanged — passed; attn is the target)
// ---------------------------------------------------------------------------
template <bool OUT_BF16>
__launch_bounds__(256)
__global__ void gemm_kernel(const bf16* __restrict__ A,
                            const bf16* __restrict__ Bt,
                            const float* __restrict__ bias,
                            void* __restrict__ Out, int Ndim, int Kdim) {
  __shared__ bf16 lds_a[128 * 64];
  __shared__ bf16 lds_b[128 * 64];
  const int tid = threadIdx.x;
  const int l = tid & 63, wid = tid >> 6;
  const int wm = wid >> 1, wn = wid & 1;
  const int lr = l & 15, lh = l >> 4;
  const int m0 = blockIdx.x * 128, n0 = blockIdx.y * 128;
  const int r8 = l >> 3, g8 = (l & 7) * 8;

  f32x4 acc[4][4] = {};

  for (int k0 = 0; k0 < Kdim; k0 += 64) {
    __syncthreads();
#pragma unroll
    for (int i = 0; i < 4; ++i) {
      const int c = wid * 4 + i;
      const int row = c * 8 + r8;
      gload16(A  + (size_t)(m0 + row) * Kdim + k0 + g8, &lds_a[c * 512]);
      gload16(Bt + (size_t)(n0 + row) * Kdim + k0 + g8, &lds_b[c * 512]);
    }
    __syncthreads();
#pragma unroll
    for (int kk = 0; kk < 2; ++kk) {
      bf16x8 af[4], bfr[4];
#pragma unroll
      for (int mi = 0; mi < 4; ++mi)
        af[mi] = *(const bf16x8*)&lds_a[(wm * 64 + mi * 16 + lr) * 64 + kk * 32 + lh * 8];
#pragma unroll
      for (int ni = 0; ni < 4; ++ni)
        bfr[ni] = *(const bf16x8*)&lds_b[(wn * 64 + ni * 16 + lr) * 64 + kk * 32 + lh * 8];
#pragma unroll
      for (int mi = 0; mi < 4; ++mi)
#pragma unroll
        for (int ni = 0; ni < 4; ++ni)
          acc[mi][ni] = __builtin_amdgcn_mfma_f32_16x16x32_bf16(
              af[mi], bfr[ni], acc[mi][ni], 0, 0, 0);
    }
  }
#pragma unroll
  for (int ni = 0; ni < 4; ++ni) {
    int col = n0 + wn * 64 + ni * 16 + lr;
    float bv = bias[col];
#pragma unroll
    for (int mi = 0; mi < 4; ++mi) {
#pragma unroll
      for (int r = 0; r < 4; ++r) {
        int row = m0 + wm * 64 + mi * 16 + lh * 4 + r;
        float v = acc[mi][ni][r] + bv;
        if (OUT_BF16)
          ((bf16*)Out)[(size_t)row * Ndim + col] = (bf16)v;
        else
          ((float*)Out)[(size_t)row * Ndim + col] = v;
      }
    }
  }
}

// ---------------------------------------------------------------------------
// Flash attention (causal), double-buffered + async-stage split (T14) +
// SWAPPED QK^T (T12-style): s4 = mfma(K_frag, Q_frag) gives S^T, so each
// lane owns the full 16-key slice of ONE q-row (q = lane&15). Row max/sum
// are in-lane reductions + 2 shfl_xor (lanes ^16, ^32) instead of 4 rows x
// 8 chained shuffles. alpha/lsum redistributed to O's layout (q = lh*4+r)
// via 4 bpermutes. P roundtrip / V^T / O layouts unchanged.
// ---------------------------------------------------------------------------
DEV int vswz(int d, int key) {  // elem index into V^T tile [64 d][64 key]
  return (d * 64 + key) ^ ((((d & 7) ^ (d >> 3)) & 7) << 3);
}

__launch_bounds__(256)
__global__ void attn_kernel(const bf16* __restrict__ qkv, bf16* __restrict__ out) {
  __shared__ bf16 lds_k[2][64 * 64];
  __shared__ bf16 lds_vt[2][64 * 64];
  __shared__ bf16 lds_p[4][16 * 64];
  const int tid = threadIdx.x, l = tid & 63, w = tid >> 6;
  const int lr = l & 15, lh = l >> 4;
  const int qt = gridDim.x - 1 - blockIdx.x;       // longest-first
  const int bh = blockIdx.y, b = bh >> 4, h = bh & 15;
  const size_t RS = 3 * C;  // qkv row stride (elems)
  const bf16* base  = qkv + (size_t)b * T * RS;
  const bf16* kbase = base + C + h * 64;
  const bf16* vbase = base + 2 * C + h * 64;
  const int srow = tid >> 3;   // staging: row 0..31 (+32 on second step)
  const int ss   = tid & 7;    // staging: 8-elem group within row

  // Q fragments (regs, whole kernel), pre-scaled by 2^-3 (exact in bf16)
  const int q16 = qt * 64 + w * 16;
  bf16x8 qf[2];
#pragma unroll
  for (int kk = 0; kk < 2; ++kk) {
    bf16x8 qv = *(const bf16x8*)(base + (size_t)(q16 + lr) * RS + h * 64 + kk * 32 + lh * 8);
#pragma unroll
    for (int j = 0; j < 8; ++j) qf[kk][j] = (bf16)((float)qv[j] * SM_SCALE);
  }

  // per-lane softmax state for q = lr (replicated across the 4 lh lanes)
  float mq = -__builtin_inff(), lq = 0.f;
  f32x4 o[4] = {};

  // ---- prologue: stage tile 0 into buf 0
  bf16x8 pk[2], pv[2];
#pragma unroll
  for (int i = 0; i < 2; ++i) {
    int row = i * 32 + srow;
    pk[i] = *(const bf16x8*)(kbase + (size_t)row * RS + ss * 8);
    pv[i] = *(const bf16x8*)(vbase + (size_t)row * RS + ss * 8);
  }
#pragma unroll
  for (int i = 0; i < 2; ++i) {
    int row = i * 32 + srow;
    *(bf16x8*)&lds_k[0][(row * 64 + ss * 8) ^ ((row & 7) << 3)] = pk[i];
#pragma unroll
    for (int j = 0; j < 8; ++j) lds_vt[0][vswz(ss * 8 + j, row)] = pv[i][j];
  }
  __syncthreads();

  int buf = 0;
  for (int kt = 0; kt <= qt; ++kt) {
    const bf16* kb = &lds_k[buf][0];
    const bf16* vb = &lds_vt[buf][0];
    // ---- issue prefetch of tile kt+1 (latency hides under compute below)
    if (kt < qt) {
#pragma unroll
      for (int i = 0; i < 2; ++i) {
        int row = i * 32 + srow;
        pk[i] = *(const bf16x8*)(kbase + (size_t)((kt + 1) * 64 + row) * RS + ss * 8);
        pv[i] = *(const bf16x8*)(vbase + (size_t)((kt + 1) * 64 + row) * RS + ss * 8);
      }
    }

    // ---- S^T = K (Q*scale)^T : s4[kn][r] = S[key=kn*16+lh*4+r][q=lr]
    f32x4 s4[4] = {};
    __builtin_amdgcn_s_setprio(1);
#pragma unroll
    for (int kk = 0; kk < 2; ++kk) {
#pragma unroll
      for (int kn = 0; kn < 4; ++kn) {
        int key = kn * 16 + lr;  // A-frag: lane lr holds key-row kn*16+lr
        bf16x8 kf = *(const bf16x8*)&kb[(key * 64 + kk * 32 + lh * 8) ^ ((key & 7) << 3)];
        s4[kn] = __builtin_amdgcn_mfma_f32_16x16x32_bf16(kf, qf[kk], s4[kn], 0, 0, 0);
      }
    }
    __builtin_amdgcn_s_setprio(0);
    // ---- causal mask (diagonal tile only): mask key_local > q_local
    if (kt == qt) {
      const int qloc = w * 16 + lr;
#pragma unroll
      for (int kn = 0; kn < 4; ++kn)
#pragma unroll
        for (int r = 0; r < 4; ++r)
          if ((kn * 16 + lh * 4 + r) > qloc) s4[kn][r] = -__builtin_inff();
    }
    // ---- online softmax: in-lane over 16 keys + 2 shfl (q = lr)
    float pm = s4[0][0];
#pragma unroll
    for (int kn = 0; kn < 4; ++kn)
#pragma unroll
      for (int r = 0; r < 4; ++r) pm = fmaxf(pm, s4[kn][r]);
    pm = fmaxf(pm, __shfl_xor(pm, 16));
    pm = fmaxf(pm, __shfl_xor(pm, 32));
    const float mnew = fmaxf(mq, pm);
    const float alpha_q = __expf(mq - mnew);  // for q = lr
    mq = mnew;
    float ssum = 0.f;
#pragma unroll
    for (int kn = 0; kn < 4; ++kn)
#pragma unroll
      for (int r = 0; r < 4; ++r) {
        float p = __expf(s4[kn][r] - mnew);
        s4[kn][r] = p;
        ssum += p;
      }
    ssum += __shfl_xor(ssum, 16);
    ssum += __shfl_xor(ssum, 32);
    lq = lq * alpha_q + ssum;
    // ---- rescale O (O layout: q = lh*4+r): fetch alpha[q'] via bpermute
    float al[4];
#pragma unroll
    for (int r = 0; r < 4; ++r) al[r] = __shfl(alpha_q, lh * 4 + r);
#pragma unroll
    for (int ni = 0; ni < 4; ++ni)
#pragma unroll
      for (int r = 0; r < 4; ++r) o[ni][r] *= al[r];
    // ---- P -> LDS in PV A-frag layout (row = q = lr), 8B packed stores
#pragma unroll
    for (int kn = 0; kn < 4; ++kn) {
      bf16x4 pb;
#pragma unroll
      for (int r = 0; r < 4; ++r) pb[r] = (bf16)s4[kn][r];
      *(bf16x4*)&lds_p[w][(lr * 64 + kn * 16 + lh * 4) ^ ((lr & 7) << 3)] = pb;
    }
    // ---- O += P V  (same-wave LDS write->read ordered via lgkmcnt)
    __builtin_amdgcn_s_setprio(1);
#pragma unroll
    for (int kk = 0; kk < 2; ++kk) {
      bf16x8 pf = *(const bf16x8*)&lds_p[w][(lr * 64 + kk * 32 + lh * 8) ^ ((lr & 7) << 3)];
#pragma unroll
      for (int ni = 0; ni < 4; ++ni) {
        int d = ni * 16 + lr;
        bf16x8 vf = *(const bf16x8*)&vb[vswz(d, kk * 32 + lh * 8)];
        o[ni] = __builtin_amdgcn_mfma_f32_16x16x32_bf16(pf, vf, o[ni], 0, 0, 0);
      }
    }
    __builtin_amdgcn_s_setprio(0);

    // ---- write prefetched tile into buf^1, single barrier, swap
    if (kt < qt) {
#pragma unroll
      for (int i = 0; i < 2; ++i) {
        int row = i * 32 + srow;
        *(bf16x8*)&lds_k[buf ^ 1][(row * 64 + ss * 8) ^ ((row & 7) << 3)] = pk[i];
#pragma unroll
        for (int j = 0; j < 8; ++j) lds_vt[buf ^ 1][vswz(ss * 8 + j, row)] = pv[i][j];
      }
      __syncthreads();
      buf ^= 1;
    }
  }
  // ---- epilogue: fetch lsum for O's q-rows, normalize, store [B*T][C]
  float lden[4];
#pragma unroll
  for (int r = 0; r < 4; ++r) lden[r] = __shfl(lq, lh * 4 + r);
  bf16* op = out + (size_t)b * T * C + h * 64;
#pragma unroll
  for (int ni = 0; ni < 4; ++ni)
#pragma unroll
    for (int r = 0; r < 4; ++r) {
      int q = q16 + lh * 4 + r;
      op[(size_t)q * C + ni * 16 + lr] = (bf16)(o[ni][r] / lden[r]);
    }
}

// ---------------------------------------------------------------------------
extern "C" void kernel_launch(void* const* d_in, const int* in_sizes, int n_in,
                              void* d_out, int out_size, void* d_ws, size_t ws_size,
                              hipStream_t stream) {
  const float* x     = (const float*)d_in[0];
  const float* Wqkv  = (const float*)d_in[1];
  const float* bqkv  = (const float*)d_in[2];
  const float* Wproj = (const float*)d_in[3];
  const float* bproj = (const float*)d_in[4];
  float* out = (float*)d_out;

  char* ws = (char*)d_ws;
  bf16* qkv      = (bf16*)(ws);             // 8192*3072*2 = 50331648 B
  bf16* wqkvt    = (bf16*)(ws + 50331648);  // 3072*1024*2 =  6291456 B
  bf16* wprojt   = (bf16*)(ws + 56623104);  // 1024*1024*2 =  2097152 B
  bf16* attn_out = (bf16*)(ws + 58720256);  // 8192*1024*2 = 16777216 B (total 72 MiB)
  bf16* x_bf16   = attn_out;  // aliased: x_bf16 dead before attn writes attn_out

  convert_kernel<<<dim3(M * C / (256 * 8)), 256, 0, stream>>>(x, x_bf16);
  transpose_conv_kernel<<<dim3(N1 / 32, C / 32), 256, 0, stream>>>(Wqkv, wqkvt, C, N1);
  transpose_conv_kernel<<<dim3(C / 32, C / 32), 256, 0, stream>>>(Wproj, wprojt, C, C);
  gemm_kernel<true><<<dim3(M / 128, N1 / 128), 256, 0, stream>>>(
      x_bf16, wqkvt, bqkv, qkv, N1, C);
  attn_kernel<<<dim3(T / 64, Bsz * H), 256, 0, stream>>>(qkv, attn_out);
  gemm_kernel<false><<<dim3(M / 128, C / 128), 256, 0, stream>>>(
      attn_out, wprojt, bproj, out, C, C);
}

// Round 6
// 300.055 us; speedup vs baseline: 1.7643x; 1.1822x over previous
//
#include <hip/hip_runtime.h>
#include <hip/hip_bf16.h>

typedef __bf16 bf16;
typedef __bf16 bf16x4 __attribute__((ext_vector_type(4)));
typedef __bf16 bf16x8 __attribute__((ext_vector_type(8)));
typedef float  f32x4  __attribute__((ext_vector_type(4)));

#define DEV static __device__ __forceinline__

static constexpr int Bsz = 4, T = 2048, C = 1024, H = 16;
static constexpr int M  = Bsz * T;   // 8192
static constexpr int N1 = 3 * C;     // 3072
static constexpr float SM_SCALE = 0.125f;  // D^-0.5 = 2^-3, exact in bf16

// async global->LDS, 16B per lane. LDS dest is wave-uniform base + lane*16.
DEV void gload16(const bf16* g, bf16* l) {
  __builtin_amdgcn_global_load_lds(
      (const __attribute__((address_space(1))) void*)g,
      (__attribute__((address_space(3))) void*)l, 16, 0, 0);
}

// ---------------------------------------------------------------------------
// fp32 -> bf16 convert (vectorized, memory-bound)
// ---------------------------------------------------------------------------
__launch_bounds__(256)
__global__ void convert_kernel(const float* __restrict__ in, bf16* __restrict__ out) {
  const size_t i = ((size_t)blockIdx.x * 256 + threadIdx.x) * 8;
  f32x4 a = *(const f32x4*)(in + i);
  f32x4 b = *(const f32x4*)(in + i + 4);
  *(bf16x4*)(out + i)     = __builtin_convertvector(a, bf16x4);
  *(bf16x4*)(out + i + 4) = __builtin_convertvector(b, bf16x4);
}

// ---------------------------------------------------------------------------
// Transpose + fp32->bf16 convert:  in[K][N] (fp32) -> out[N][K] (bf16)
// ---------------------------------------------------------------------------
__launch_bounds__(256)
__global__ void transpose_conv_kernel(const float* __restrict__ in,
                                      bf16* __restrict__ out, int K, int N) {
  __shared__ float t[32][33];
  const int n0 = blockIdx.x * 32, k0 = blockIdx.y * 32;
  const int tx = threadIdx.x & 31, ty = threadIdx.x >> 5;  // ty in 0..7
#pragma unroll
  for (int j = 0; j < 4; ++j)
    t[ty + j * 8][tx] = in[(size_t)(k0 + ty + j * 8) * N + n0 + tx];
  __syncthreads();
#pragma unroll
  for (int j = 0; j < 4; ++j)
    out[(size_t)(n0 + ty + j * 8) * K + k0 + tx] = (bf16)t[tx][ty + j * 8];
}

// ---------------------------------------------------------------------------
// GEMM (m97 structure): Out[M][N] = A[M][K] @ Bt[N][K]^T + bias[N]
// (unchanged — passed; attn is the target)
// ---------------------------------------------------------------------------
template <bool OUT_BF16>
__launch_bounds__(256)
__global__ void gemm_kernel(const bf16* __restrict__ A,
                            const bf16* __restrict__ Bt,
                            const float* __restrict__ bias,
                            void* __restrict__ Out, int Ndim, int Kdim) {
  __shared__ bf16 lds_a[128 * 64];
  __shared__ bf16 lds_b[128 * 64];
  const int tid = threadIdx.x;
  const int l = tid & 63, wid = tid >> 6;
  const int wm = wid >> 1, wn = wid & 1;
  const int lr = l & 15, lh = l >> 4;
  const int m0 = blockIdx.x * 128, n0 = blockIdx.y * 128;
  const int r8 = l >> 3, g8 = (l & 7) * 8;

  f32x4 acc[4][4] = {};

  for (int k0 = 0; k0 < Kdim; k0 += 64) {
    __syncthreads();
#pragma unroll
    for (int i = 0; i < 4; ++i) {
      const int c = wid * 4 + i;
      const int row = c * 8 + r8;
      gload16(A  + (size_t)(m0 + row) * Kdim + k0 + g8, &lds_a[c * 512]);
      gload16(Bt + (size_t)(n0 + row) * Kdim + k0 + g8, &lds_b[c * 512]);
    }
    __syncthreads();
#pragma unroll
    for (int kk = 0; kk < 2; ++kk) {
      bf16x8 af[4], bfr[4];
#pragma unroll
      for (int mi = 0; mi < 4; ++mi)
        af[mi] = *(const bf16x8*)&lds_a[(wm * 64 + mi * 16 + lr) * 64 + kk * 32 + lh * 8];
#pragma unroll
      for (int ni = 0; ni < 4; ++ni)
        bfr[ni] = *(const bf16x8*)&lds_b[(wn * 64 + ni * 16 + lr) * 64 + kk * 32 + lh * 8];
#pragma unroll
      for (int mi = 0; mi < 4; ++mi)
#pragma unroll
        for (int ni = 0; ni < 4; ++ni)
          acc[mi][ni] = __builtin_amdgcn_mfma_f32_16x16x32_bf16(
              af[mi], bfr[ni], acc[mi][ni], 0, 0, 0);
    }
  }
#pragma unroll
  for (int ni = 0; ni < 4; ++ni) {
    int col = n0 + wn * 64 + ni * 16 + lr;
    float bv = bias[col];
#pragma unroll
    for (int mi = 0; mi < 4; ++mi) {
#pragma unroll
      for (int r = 0; r < 4; ++r) {
        int row = m0 + wm * 64 + mi * 16 + lh * 4 + r;
        float v = acc[mi][ni][r] + bv;
        if (OUT_BF16)
          ((bf16*)Out)[(size_t)row * Ndim + col] = (bf16)v;
        else
          ((float*)Out)[(size_t)row * Ndim + col] = v;
      }
    }
  }
}

// ---------------------------------------------------------------------------
// Flash attention (causal), swapped QK^T + T14 dbuf prefetch + BALANCED
// PERSISTENT GRID: 1024 blocks (= exactly 4/CU capacity at 40KB LDS).
// Block p (bh=p>>4, j=p&15) runs TWO q-tiles: qt = 31-j then qt = j —
// every block does exactly 33 tile-steps (zero imbalance, no dispatch
// churn, no drain tail). Round-5 occupancy was 16% vs 50% cap because of
// the 1..32-tile triangular work spread across 2048 blocks.
// ---------------------------------------------------------------------------
DEV int vswz(int d, int key) {  // elem index into V^T tile [64 d][64 key]
  return (d * 64 + key) ^ ((((d & 7) ^ (d >> 3)) & 7) << 3);
}

__launch_bounds__(256)
__global__ void attn_kernel(const bf16* __restrict__ qkv, bf16* __restrict__ out) {
  __shared__ bf16 lds_k[2][64 * 64];
  __shared__ bf16 lds_vt[2][64 * 64];
  __shared__ bf16 lds_p[4][16 * 64];
  const int tid = threadIdx.x, l = tid & 63, w = tid >> 6;
  const int lr = l & 15, lh = l >> 4;
  const int p = blockIdx.x;
  const int bh = p >> 4, jj = p & 15;
  const int b = bh >> 4, h = bh & 15;
  const size_t RS = 3 * C;  // qkv row stride (elems)
  const bf16* base  = qkv + (size_t)b * T * RS;
  const bf16* kbase = base + C + h * 64;
  const bf16* vbase = base + 2 * C + h * 64;
  const int srow = tid >> 3;   // staging: row 0..31 (+32 on second step)
  const int ss   = tid & 7;    // staging: 8-elem group within row
  bf16* op = out + (size_t)b * T * C + h * 64;

  for (int it = 0; it < 2; ++it) {
    const int qt = it ? jj : 31 - jj;   // long item first
    // Q fragments (regs), pre-scaled by 2^-3 (exact in bf16)
    const int q16 = qt * 64 + w * 16;
    bf16x8 qf[2];
#pragma unroll
    for (int kk = 0; kk < 2; ++kk) {
      bf16x8 qv = *(const bf16x8*)(base + (size_t)(q16 + lr) * RS + h * 64 + kk * 32 + lh * 8);
#pragma unroll
      for (int j = 0; j < 8; ++j) qf[kk][j] = (bf16)((float)qv[j] * SM_SCALE);
    }

    // per-lane softmax state for q = lr (replicated across the 4 lh lanes)
    float mq = -__builtin_inff(), lq = 0.f;
    f32x4 o[4] = {};

    // ---- prologue: stage tile 0 into buf 0
    bf16x8 pk[2], pv[2];
#pragma unroll
    for (int i = 0; i < 2; ++i) {
      int row = i * 32 + srow;
      pk[i] = *(const bf16x8*)(kbase + (size_t)row * RS + ss * 8);
      pv[i] = *(const bf16x8*)(vbase + (size_t)row * RS + ss * 8);
    }
    __syncthreads();  // item 0 readers done before item 1 prologue overwrites
#pragma unroll
    for (int i = 0; i < 2; ++i) {
      int row = i * 32 + srow;
      *(bf16x8*)&lds_k[0][(row * 64 + ss * 8) ^ ((row & 7) << 3)] = pk[i];
#pragma unroll
      for (int j = 0; j < 8; ++j) lds_vt[0][vswz(ss * 8 + j, row)] = pv[i][j];
    }
    __syncthreads();

    int buf = 0;
    for (int kt = 0; kt <= qt; ++kt) {
      const bf16* kb = &lds_k[buf][0];
      const bf16* vb = &lds_vt[buf][0];
      // ---- issue prefetch of tile kt+1 (latency hides under compute below)
      if (kt < qt) {
#pragma unroll
        for (int i = 0; i < 2; ++i) {
          int row = i * 32 + srow;
          pk[i] = *(const bf16x8*)(kbase + (size_t)((kt + 1) * 64 + row) * RS + ss * 8);
          pv[i] = *(const bf16x8*)(vbase + (size_t)((kt + 1) * 64 + row) * RS + ss * 8);
        }
      }

      // ---- S^T = K (Q*scale)^T : s4[kn][r] = S[key=kn*16+lh*4+r][q=lr]
      f32x4 s4[4] = {};
      __builtin_amdgcn_s_setprio(1);
#pragma unroll
      for (int kk = 0; kk < 2; ++kk) {
#pragma unroll
        for (int kn = 0; kn < 4; ++kn) {
          int key = kn * 16 + lr;  // A-frag: lane lr holds key-row kn*16+lr
          bf16x8 kf = *(const bf16x8*)&kb[(key * 64 + kk * 32 + lh * 8) ^ ((key & 7) << 3)];
          s4[kn] = __builtin_amdgcn_mfma_f32_16x16x32_bf16(kf, qf[kk], s4[kn], 0, 0, 0);
        }
      }
      __builtin_amdgcn_s_setprio(0);
      // ---- causal mask (diagonal tile only): mask key_local > q_local
      if (kt == qt) {
        const int qloc = w * 16 + lr;
#pragma unroll
        for (int kn = 0; kn < 4; ++kn)
#pragma unroll
          for (int r = 0; r < 4; ++r)
            if ((kn * 16 + lh * 4 + r) > qloc) s4[kn][r] = -__builtin_inff();
      }
      // ---- online softmax: in-lane over 16 keys + 2 shfl (q = lr)
      float pm = s4[0][0];
#pragma unroll
      for (int kn = 0; kn < 4; ++kn)
#pragma unroll
        for (int r = 0; r < 4; ++r) pm = fmaxf(pm, s4[kn][r]);
      pm = fmaxf(pm, __shfl_xor(pm, 16));
      pm = fmaxf(pm, __shfl_xor(pm, 32));
      const float mnew = fmaxf(mq, pm);
      const float alpha_q = __expf(mq - mnew);  // for q = lr
      mq = mnew;
      float ssum = 0.f;
#pragma unroll
      for (int kn = 0; kn < 4; ++kn)
#pragma unroll
        for (int r = 0; r < 4; ++r) {
          float p2 = __expf(s4[kn][r] - mnew);
          s4[kn][r] = p2;
          ssum += p2;
        }
      // ---- P -> LDS early (lgkm drain overlaps the shuffles/rescale below)
#pragma unroll
      for (int kn = 0; kn < 4; ++kn) {
        bf16x4 pb;
#pragma unroll
        for (int r = 0; r < 4; ++r) pb[r] = (bf16)s4[kn][r];
        *(bf16x4*)&lds_p[w][(lr * 64 + kn * 16 + lh * 4) ^ ((lr & 7) << 3)] = pb;
      }
      ssum += __shfl_xor(ssum, 16);
      ssum += __shfl_xor(ssum, 32);
      lq = lq * alpha_q + ssum;
      // ---- rescale O (O layout: q = lh*4+r): fetch alpha[q'] via bpermute
      float al[4];
#pragma unroll
      for (int r = 0; r < 4; ++r) al[r] = __shfl(alpha_q, lh * 4 + r);
#pragma unroll
      for (int ni = 0; ni < 4; ++ni)
#pragma unroll
        for (int r = 0; r < 4; ++r) o[ni][r] *= al[r];
      // ---- O += P V  (same-wave LDS write->read ordered via lgkmcnt)
      __builtin_amdgcn_s_setprio(1);
#pragma unroll
      for (int kk = 0; kk < 2; ++kk) {
        bf16x8 pf = *(const bf16x8*)&lds_p[w][(lr * 64 + kk * 32 + lh * 8) ^ ((lr & 7) << 3)];
#pragma unroll
        for (int ni = 0; ni < 4; ++ni) {
          int d = ni * 16 + lr;
          bf16x8 vf = *(const bf16x8*)&vb[vswz(d, kk * 32 + lh * 8)];
          o[ni] = __builtin_amdgcn_mfma_f32_16x16x32_bf16(pf, vf, o[ni], 0, 0, 0);
        }
      }
      __builtin_amdgcn_s_setprio(0);

      // ---- write prefetched tile into buf^1, single barrier, swap
      if (kt < qt) {
#pragma unroll
        for (int i = 0; i < 2; ++i) {
          int row = i * 32 + srow;
          *(bf16x8*)&lds_k[buf ^ 1][(row * 64 + ss * 8) ^ ((row & 7) << 3)] = pk[i];
#pragma unroll
          for (int j = 0; j < 8; ++j) lds_vt[buf ^ 1][vswz(ss * 8 + j, row)] = pv[i][j];
        }
        __syncthreads();
        buf ^= 1;
      }
    }
    // ---- epilogue: fetch lsum for O's q-rows, normalize, store [B*T][C]
    float lden[4];
#pragma unroll
    for (int r = 0; r < 4; ++r) lden[r] = __shfl(lq, lh * 4 + r);
#pragma unroll
    for (int ni = 0; ni < 4; ++ni)
#pragma unroll
      for (int r = 0; r < 4; ++r) {
        int q = q16 + lh * 4 + r;
        op[(size_t)q * C + ni * 16 + lr] = (bf16)(o[ni][r] / lden[r]);
      }
  }
}

// ---------------------------------------------------------------------------
extern "C" void kernel_launch(void* const* d_in, const int* in_sizes, int n_in,
                              void* d_out, int out_size, void* d_ws, size_t ws_size,
                              hipStream_t stream) {
  const float* x     = (const float*)d_in[0];
  const float* Wqkv  = (const float*)d_in[1];
  const float* bqkv  = (const float*)d_in[2];
  const float* Wproj = (const float*)d_in[3];
  const float* bproj = (const float*)d_in[4];
  float* out = (float*)d_out;

  char* ws = (char*)d_ws;
  bf16* qkv      = (bf16*)(ws);             // 8192*3072*2 = 50331648 B
  bf16* wqkvt    = (bf16*)(ws + 50331648);  // 3072*1024*2 =  6291456 B
  bf16* wprojt   = (bf16*)(ws + 56623104);  // 1024*1024*2 =  2097152 B
  bf16* attn_out = (bf16*)(ws + 58720256);  // 8192*1024*2 = 16777216 B (total 72 MiB)
  bf16* x_bf16   = attn_out;  // aliased: x_bf16 dead before attn writes attn_out

  convert_kernel<<<dim3(M * C / (256 * 8)), 256, 0, stream>>>(x, x_bf16);
  transpose_conv_kernel<<<dim3(N1 / 32, C / 32), 256, 0, stream>>>(Wqkv, wqkvt, C, N1);
  transpose_conv_kernel<<<dim3(C / 32, C / 32), 256, 0, stream>>>(Wproj, wprojt, C, C);
  gemm_kernel<true><<<dim3(M / 128, N1 / 128), 256, 0, stream>>>(
      x_bf16, wqkvt, bqkv, qkv, N1, C);
  attn_kernel<<<dim3(Bsz * H * 16), 256, 0, stream>>>(qkv, attn_out);
  gemm_kernel<false><<<dim3(M / 128, C / 128), 256, 0, stream>>>(
      attn_out, wprojt, bproj, out, C, C);
}